// Round 15
// baseline (33.065 us; speedup 1.0000x reference)
//
#include <hip/hip_runtime.h>
#include <math.h>

constexpr int NB    = 128;
constexpr int NPAIR = NB * (NB - 1) / 2;        // 8128
constexpr int NANG  = NB - 2;                   // 126
constexpr int NDIH  = NB - 3;                   // 125
constexpr int ROW   = NPAIR + NANG + 2 * NDIH;  // 8504

// Wave-private LDS-image scheme: wave w computes off-band 8w+1..8w+8 into
// sfeat[] (band-of-4 compute, two position halves), then flushes ITS OWN
// contiguous 16B-aligned flat range [B(8w+1), B(8w+9)) as dwordx4 — no
// barriers after staging, so stores issue continuously (no chip-wide phase
// alignment). Tests 16B/lane store width with overlap, vs R13's 4B/lane.
__global__ __launch_bounds__(1024, 8) void protein_feat_kernel(
        const float* __restrict__ data, float* __restrict__ out) {
    __shared__ float4 s4[NB];        // (x,y,z,0) per bead      (2 KB)
    __shared__ float  sfeat[NPAIR];  // distance image          (31.8 KB)
    const int b = blockIdx.x;
    const int t = threadIdx.x;       // 0..1023
    const int l = t & 63;            // lane
    const int w = t >> 6;            // wave 0..15
    const float* src = data + (size_t)b * (NB * 3);

    if (t < NB)
        s4[t] = make_float4(src[3 * t], src[3 * t + 1], src[3 * t + 2], 0.0f);
    __syncthreads();                 // the ONLY barrier

    float* orow = out + (size_t)b * ROW;

    // Band register windows for both position halves (P = l and P = l+64):
    // beads l..l-3 and l+64..l+61.
    float pxL[4], pyL[4], pzL[4], pxH[4], pyH[4], pzH[4];
    #pragma unroll
    for (int k = 0; k < 4; ++k) {
        int iL = l - k; if (iL < 0) iL = 0;      // clamped; masked at store
        float4 v = s4[iL];
        pxL[k] = v.x; pyL[k] = v.y; pzL[k] = v.z;
        float4 u = s4[l + 64 - k];               // 61..127: always in range
        pxH[k] = u.x; pyH[k] = u.y; pzH[k] = u.z;
    }

    const int off_base = 8 * w + 1;  // wave-private rows off_base..off_base+7

    #pragma unroll
    for (int m = 0; m < 2; ++m) {
        const int off0 = off_base + 4 * m;
        const int len0 = NB - off0;
        const int bk0  = (off0 - 1) * (2 * NB - off0) / 2;  // B(off0)
        const int bk1  = bk0 + len0;
        const int bk2  = bk1 + len0 - 1;
        const int bk3  = bk2 + len0 - 2;

        // Low half: P = l. Valid pos for row off0+k: P-k in [0, len0-k-1]
        // <=> P <= len0-1 (guard below) and P >= k (per-store).
        if (l < len0) {
            float4 pj = s4[l + off0];
            float dx, dy, dz, d;
            dx = pj.x - pxL[0]; dy = pj.y - pyL[0]; dz = pj.z - pzL[0];
            d = __builtin_amdgcn_sqrtf(dx*dx + dy*dy + dz*dz);
            sfeat[bk0 + l] = d;
            dx = pj.x - pxL[1]; dy = pj.y - pyL[1]; dz = pj.z - pzL[1];
            d = __builtin_amdgcn_sqrtf(dx*dx + dy*dy + dz*dz);
            if (l >= 1) sfeat[bk1 + l - 1] = d;
            dx = pj.x - pxL[2]; dy = pj.y - pyL[2]; dz = pj.z - pzL[2];
            d = __builtin_amdgcn_sqrtf(dx*dx + dy*dy + dz*dz);
            if (l >= 2) sfeat[bk2 + l - 2] = d;
            dx = pj.x - pxL[3]; dy = pj.y - pyL[3]; dz = pj.z - pzL[3];
            d = __builtin_amdgcn_sqrtf(dx*dx + dy*dy + dz*dz);
            if (l >= 3) sfeat[bk3 + l - 3] = d;
        }
        // High half: P = l + 64 (P >= k always).
        const int P = l + 64;
        if (P < len0) {
            float4 pj = s4[P + off0];
            float dx, dy, dz, d;
            dx = pj.x - pxH[0]; dy = pj.y - pyH[0]; dz = pj.z - pzH[0];
            d = __builtin_amdgcn_sqrtf(dx*dx + dy*dy + dz*dz);
            sfeat[bk0 + P] = d;
            dx = pj.x - pxH[1]; dy = pj.y - pyH[1]; dz = pj.z - pzH[1];
            d = __builtin_amdgcn_sqrtf(dx*dx + dy*dy + dz*dz);
            sfeat[bk1 + P - 1] = d;
            dx = pj.x - pxH[2]; dy = pj.y - pyH[2]; dz = pj.z - pzH[2];
            d = __builtin_amdgcn_sqrtf(dx*dx + dy*dy + dz*dz);
            sfeat[bk2 + P - 2] = d;
            dx = pj.x - pxH[3]; dy = pj.y - pyH[3]; dz = pj.z - pzH[3];
            d = __builtin_amdgcn_sqrtf(dx*dx + dy*dy + dz*dz);
            sfeat[bk3 + P - 3] = d;
        }
    }

    // Flush own band: flat floats [B(8w+1), B(8w+9)) = 988-64w values
    // (w=15: 28). Base and count divisible by 4 -> aligned dwordx4 stream.
    // Intra-wave ds_write -> ds_read ordering handled by compiler lgkmcnt.
    {
        const int base4 = ((off_base - 1) * (2 * NB - off_base) / 2) >> 2;
        const int nf4   = (988 - 64 * w) >> 2;                // 247 - 16w
        const float4* sf4 = (const float4*)sfeat;
        float4* dst = (float4*)orow;                          // 16B-aligned
        for (int f = l; f < nf4; f += 64)
            dst[base4 + f] = sf4[base4 + f];
    }

    // ---- Angles (126) + dihedral cos (125) + dihedral sin (125): direct
    // scalar stores (2% of bytes), t<376 only; reads only s4 (staged).
    const int v = t;
    if (v < NANG + 2 * NDIH) {
        if (v < NANG) {
            int a = v;
            float4 p0 = s4[a], p1 = s4[a + 1], p2 = s4[a + 2];
            float a0x = p1.x - p0.x, a0y = p1.y - p0.y, a0z = p1.z - p0.z;
            float a1x = p2.x - p1.x, a1y = p2.y - p1.y, a1z = p2.z - p1.z;
            float d  = a0x * a1x + a0y * a1y + a0z * a1z;
            float r0 = rsqrtf(a0x * a0x + a0y * a0y + a0z * a0z);
            float r1 = rsqrtf(a1x * a1x + a1y * a1y + a1z * a1z);
            float c  = d * r0 * r1;
            c = fminf(1.0f, fmaxf(-1.0f, c));
            orow[NPAIR + a] = acosf(c);
        } else {
            int a = (v < NANG + NDIH) ? (v - NANG) : (v - NANG - NDIH);
            float4 p0 = s4[a], p1 = s4[a + 1], p2 = s4[a + 2], p3 = s4[a + 3];
            float e0x = p1.x - p0.x, e0y = p1.y - p0.y, e0z = p1.z - p0.z;
            float e1x = p2.x - p1.x, e1y = p2.y - p1.y, e1z = p2.z - p1.z;
            float e2x = p3.x - p2.x, e2y = p3.y - p2.y, e2z = p3.z - p2.z;
            float c0x = e0y * e1z - e0z * e1y;
            float c0y = e0z * e1x - e0x * e1z;
            float c0z = e0x * e1y - e0y * e1x;
            float c1x = e1y * e2z - e1z * e2y;
            float c1y = e1z * e2x - e1x * e2z;
            float c1z = e1x * e2y - e1y * e2x;
            float rn0 = rsqrtf(c0x * c0x + c0y * c0y + c0z * c0z);
            if (v < NANG + NDIH) {
                float d   = c0x * c1x + c0y * c1y + c0z * c1z;
                float rn1 = rsqrtf(c1x * c1x + c1y * c1y + c1z * c1z);
                orow[NPAIR + NANG + a] = d * rn0 * rn1;
            } else {
                float qx = c1y * e1z - c1z * e1y;   // plane = c1 x e1
                float qy = c1z * e1x - c1x * e1z;
                float qz = c1x * e1y - c1y * e1x;
                float d  = c0x * qx + c0y * qy + c0z * qz;
                float rp = rsqrtf(qx * qx + qy * qy + qz * qz);
                orow[NPAIR + NANG + NDIH + a] = d * rn0 * rp;
            }
        }
    }
}

extern "C" void kernel_launch(void* const* d_in, const int* in_sizes, int n_in,
                              void* d_out, int out_size, void* d_ws, size_t ws_size,
                              hipStream_t stream) {
    const float* data = (const float*)d_in[0];
    float* out = (float*)d_out;
    const int batch = in_sizes[0] / (NB * 3);   // 4096
    protein_feat_kernel<<<batch, 1024, 0, stream>>>(data, out);
}